// Round 2
// baseline (1457.054 us; speedup 1.0000x reference)
//
#include <hip/hip_runtime.h>

#define BB 256
#define HH 1024
#define MM 256
#define HS 128
#define NH 129  // HS+1

__device__ __forceinline__ float sigmoidf_(float x) { return 1.0f / (1.0f + expf(-x)); }
__device__ __forceinline__ float gumbelf_(float u) { return -logf(1e-20f - logf(1e-20f + u)); }

// read_head = tanh(input_ @ W_im + h_0 @ W_hm)   (B, NH)
__global__ __launch_bounds__(256) void k_heads(const float* __restrict__ input_,
                                               const float* __restrict__ h0,
                                               const float* __restrict__ W_im,
                                               const float* __restrict__ W_hm,
                                               float* __restrict__ read_head) {
    __shared__ float sx[HH], sh[HH];
    int b = blockIdx.x;
    for (int i = threadIdx.x; i < HH; i += blockDim.x) {
        sx[i] = input_[b * HH + i];
        sh[i] = h0[b * HH + i];
    }
    __syncthreads();
    int j = threadIdx.x;
    if (j < NH) {
        float acc = 0.f;
        for (int h = 0; h < HH; ++h)
            acc += sx[h] * W_im[h * NH + j] + sh[h] * W_hm[h * NH + j];
        read_head[b * NH + j] = tanhf(acc);
    }
}

// v[b,h] = sum_j head[b,j]*fc1_w[j,h]  (j<128);  c[b] = sum_j head[b,j]*fc1_b[j]
__global__ __launch_bounds__(256) void k_project(const float* __restrict__ head,
                                                 const float* __restrict__ fc1_w,
                                                 const float* __restrict__ fc1_b,
                                                 float* __restrict__ v,
                                                 float* __restrict__ c) {
    __shared__ float sj[NH];
    int b = blockIdx.x;
    for (int i = threadIdx.x; i < NH; i += blockDim.x) sj[i] = head[b * NH + i];
    __syncthreads();
    for (int h = threadIdx.x; h < HH; h += blockDim.x) {
        float acc = 0.f;
        for (int j = 0; j < HS; ++j) acc += sj[j] * fc1_w[j * HH + h];
        v[b * HH + h] = acc;
    }
    if (threadIdx.x == 0) {
        float acc = 0.f;
        for (int j = 0; j < HS; ++j) acc += sj[j] * fc1_b[j];
        c[b] = acc;
    }
}

// sg[b,m] = sum_h mem_eff[b,m,h]*v[b,h] + c[b] + head[b,128]*sigmoid(last_usage[b,m]) + gumbel(u[b,m])
__global__ __launch_bounds__(256) void k_scores(const float* __restrict__ mem,
                                                const float* __restrict__ h0,
                                                const float* __restrict__ v,
                                                const float* __restrict__ c,
                                                const float* __restrict__ head,
                                                const float* __restrict__ last_usage,
                                                const float* __restrict__ u,
                                                float* __restrict__ sg_out) {
    __shared__ float sv[HH];
    int b = blockIdx.x;
    int mstart = blockIdx.y * 32;
    for (int i = threadIdx.x; i < HH; i += blockDim.x) sv[i] = v[b * HH + i];
    __syncthreads();
    int wave = threadIdx.x >> 6, lane = threadIdx.x & 63;
    for (int i = 0; i < 8; ++i) {
        int m = mstart + wave * 8 + i;
        const float* row = (m == 0) ? (h0 + (size_t)b * HH) : (mem + ((size_t)(b * MM + m)) * HH);
        float p = 0.f;
        for (int h = lane; h < HH; h += 64) p += row[h] * sv[h];
        for (int off = 32; off > 0; off >>= 1) p += __shfl_down(p, off, 64);
        if (lane == 0) {
            float lu = sigmoidf_(last_usage[b * MM + m]);
            float s = p + c[b] + head[b * NH + HS] * lu;
            sg_out[b * MM + m] = s + gumbelf_(u[b * MM + m]);  // TAU = 1
        }
    }
}

// argmax over m, gather entry row; then head1 = tanh(...); then v2, c2
__global__ __launch_bounds__(256) void k_sel1(const float* __restrict__ sg1,
                                              const float* __restrict__ mem,
                                              const float* __restrict__ h0,
                                              const float* __restrict__ input_,
                                              const float* __restrict__ W_im1,
                                              const float* __restrict__ W_hm1,
                                              const float* __restrict__ W_mm1,
                                              const float* __restrict__ bias_m1,
                                              const float* __restrict__ fc1_w,
                                              const float* __restrict__ fc1_b,
                                              float* __restrict__ entry,
                                              float* __restrict__ head1,
                                              float* __restrict__ v2,
                                              float* __restrict__ c2) {
    __shared__ float svals[256];
    __shared__ int sidx[256];
    __shared__ float se[HH], sx[HH], sh[HH];
    __shared__ float sj[NH];
    int b = blockIdx.x, t = threadIdx.x;
    svals[t] = sg1[b * MM + t];
    sidx[t] = t;
    __syncthreads();
    for (int s = 128; s > 0; s >>= 1) {
        if (t < s) {
            if (svals[t + s] > svals[t]) { svals[t] = svals[t + s]; sidx[t] = sidx[t + s]; }
        }
        __syncthreads();
    }
    int mstar = sidx[0];
    const float* row = (mstar == 0) ? (h0 + (size_t)b * HH) : (mem + ((size_t)(b * MM + mstar)) * HH);
    for (int h = t; h < HH; h += 256) {
        float e = row[h];
        se[h] = e;
        entry[b * HH + h] = e;
        sx[h] = input_[b * HH + h];
        sh[h] = h0[b * HH + h];
    }
    __syncthreads();
    if (t < NH) {
        float acc = bias_m1[t];
        for (int h = 0; h < HH; ++h)
            acc += sx[h] * W_im1[h * NH + t] + sh[h] * W_hm1[h * NH + t] + se[h] * W_mm1[h * NH + t];
        float hv = tanhf(acc);
        head1[b * NH + t] = hv;
        sj[t] = hv;
    }
    __syncthreads();
    for (int h = t; h < HH; h += 256) {
        float acc = 0.f;
        for (int j = 0; j < HS; ++j) acc += sj[j] * fc1_w[j * HH + h];
        v2[b * HH + h] = acc;
    }
    if (t == 0) {
        float acc = 0.f;
        for (int j = 0; j < HS; ++j) acc += sj[j] * fc1_b[j];
        c2[b] = acc;
    }
}

// argmax over m for y2, gather entry_o directly into o's second half
__global__ __launch_bounds__(256) void k_sel2(const float* __restrict__ sg2,
                                              const float* __restrict__ mem,
                                              const float* __restrict__ h0,
                                              float* __restrict__ out_o) {
    __shared__ float svals[256];
    __shared__ int sidx[256];
    int b = blockIdx.x, t = threadIdx.x;
    svals[t] = sg2[b * MM + t];
    sidx[t] = t;
    __syncthreads();
    for (int s = 128; s > 0; s >>= 1) {
        if (t < s) {
            if (svals[t + s] > svals[t]) { svals[t] = svals[t + s]; sidx[t] = sidx[t + s]; }
        }
        __syncthreads();
    }
    int mstar = sidx[0];
    const float* row = (mstar == 0) ? (h0 + (size_t)b * HH) : (mem + ((size_t)(b * MM + mstar)) * HH);
    for (int h = t; h < HH; h += 256) out_o[(size_t)b * 2 * HH + HH + h] = row[h];
}

// wb = sigmoid(entry@W_rh + h0@W_hh + input_@W_ih + bias)   (256 x 3072)
__global__ __launch_bounds__(256) void k_gemm_gru(const float* __restrict__ input_,
                                                  const float* __restrict__ h0,
                                                  const float* __restrict__ entry,
                                                  const float* __restrict__ W_ih,
                                                  const float* __restrict__ W_hh,
                                                  const float* __restrict__ W_rh,
                                                  const float* __restrict__ bias,
                                                  float* __restrict__ wb) {
    __shared__ float sA[64][17];
    __shared__ float sW[16][65];
    int row0 = blockIdx.y * 64;
    int col0 = blockIdx.x * 64;
    int tx = threadIdx.x & 15, ty = threadIdx.x >> 4;
    float acc[4][4] = {};
    const float* As[3] = {entry, h0, input_};
    const float* Ws[3] = {W_rh, W_hh, W_ih};
    for (int p = 0; p < 3; ++p) {
        const float* A = As[p];
        const float* W = Ws[p];
        for (int kt = 0; kt < HH; kt += 16) {
            for (int i = 0; i < 4; ++i) {
                int e = i * 256 + threadIdx.x;
                int r = e >> 4, cc = e & 15;
                sA[r][cc] = A[(size_t)(row0 + r) * HH + kt + cc];
            }
            for (int i = 0; i < 4; ++i) {
                int e = i * 256 + threadIdx.x;
                int r = e >> 6, cc = e & 63;
                sW[r][cc] = W[(size_t)(kt + r) * 3072 + col0 + cc];
            }
            __syncthreads();
            for (int k = 0; k < 16; ++k) {
                float a[4], w[4];
                for (int i = 0; i < 4; ++i) a[i] = sA[ty * 4 + i][k];
                for (int j = 0; j < 4; ++j) w[j] = sW[k][tx * 4 + j];
                for (int i = 0; i < 4; ++i)
                    for (int j = 0; j < 4; ++j) acc[i][j] += a[i] * w[j];
            }
            __syncthreads();
        }
    }
    for (int i = 0; i < 4; ++i)
        for (int j = 0; j < 4; ++j) {
            int r = row0 + ty * 4 + i, cc = col0 + tx * 4 + j;
            wb[(size_t)r * 3072 + cc] = sigmoidf_(acc[i][j] + bias[cc]);
        }
}

// S cols 0..1023 = input_@W_s1+b1 ; 1024..2047 = h0@W_s2+b2 ; 2048..3071 = entry@W_s3+b3
__global__ __launch_bounds__(256) void k_gemm_s(const float* __restrict__ input_,
                                                const float* __restrict__ h0,
                                                const float* __restrict__ entry,
                                                const float* __restrict__ W_s1,
                                                const float* __restrict__ W_s2,
                                                const float* __restrict__ W_s3,
                                                const float* __restrict__ b1,
                                                const float* __restrict__ b2,
                                                const float* __restrict__ b3,
                                                float* __restrict__ S) {
    __shared__ float sA[64][17];
    __shared__ float sW[16][65];
    int row0 = blockIdx.y * 64;
    int col0g = blockIdx.x * 64;
    int seg = col0g >> 10;
    int col0 = col0g & 1023;
    const float* A = (seg == 0) ? input_ : (seg == 1) ? h0 : entry;
    const float* W = (seg == 0) ? W_s1 : (seg == 1) ? W_s2 : W_s3;
    const float* bb = (seg == 0) ? b1 : (seg == 1) ? b2 : b3;
    int tx = threadIdx.x & 15, ty = threadIdx.x >> 4;
    float acc[4][4] = {};
    for (int kt = 0; kt < HH; kt += 16) {
        for (int i = 0; i < 4; ++i) {
            int e = i * 256 + threadIdx.x;
            int r = e >> 4, cc = e & 15;
            sA[r][cc] = A[(size_t)(row0 + r) * HH + kt + cc];
        }
        for (int i = 0; i < 4; ++i) {
            int e = i * 256 + threadIdx.x;
            int r = e >> 6, cc = e & 63;
            sW[r][cc] = W[(size_t)(kt + r) * HH + col0 + cc];
        }
        __syncthreads();
        for (int k = 0; k < 16; ++k) {
            float a[4], w[4];
            for (int i = 0; i < 4; ++i) a[i] = sA[ty * 4 + i][k];
            for (int j = 0; j < 4; ++j) w[j] = sW[k][tx * 4 + j];
            for (int i = 0; i < 4; ++i)
                for (int j = 0; j < 4; ++j) acc[i][j] += a[i] * w[j];
        }
        __syncthreads();
    }
    for (int i = 0; i < 4; ++i)
        for (int j = 0; j < 4; ++j) {
            int r = row0 + ty * 4 + i;
            // global column in S = seg*1024 + (col0 + tx*4 + j) = col0g + tx*4 + j
            S[(size_t)r * 3072 + col0g + tx * 4 + j] = acc[i][j] + bb[col0 + tx * 4 + j];
        }
}

// h_new = tanh(S1 + r*S2 + z*S3); h1 = n*h_new + (1-n)*n0 ; write h1 and o[:, :H]
__global__ __launch_bounds__(256) void k_final(const float* __restrict__ wb,
                                               const float* __restrict__ S,
                                               const float* __restrict__ h0,
                                               float* __restrict__ out) {
    int idx = blockIdx.x * 256 + threadIdx.x;
    int b = idx >> 10, h = idx & 1023;
    float r = wb[(size_t)b * 3072 + h];
    float z = wb[(size_t)b * 3072 + 1024 + h];
    float n = wb[(size_t)b * 3072 + 2048 + h];
    float s1 = S[(size_t)b * 3072 + h];
    float s2 = S[(size_t)b * 3072 + 1024 + h];
    float s3 = S[(size_t)b * 3072 + 2048 + h];
    float hn = tanhf(s1 + r * s2 + z * s3);
    float h1 = n * hn + (1.f - n) * h0[idx];
    out[idx] = h1;
    out[(size_t)BB * HH + (size_t)b * 2 * HH + h] = h1;
}

extern "C" void kernel_launch(void* const* d_in, const int* in_sizes, int n_in,
                              void* d_out, int out_size, void* d_ws, size_t ws_size,
                              hipStream_t stream) {
    const float* input_ = (const float*)d_in[0];
    const float* h0 = (const float*)d_in[1];
    const float* mem = (const float*)d_in[2];
    const float* last_usage = (const float*)d_in[3];
    const float* u1 = (const float*)d_in[4];
    const float* u2 = (const float*)d_in[5];
    const float* W_ih = (const float*)d_in[6];
    const float* W_hh = (const float*)d_in[7];
    const float* W_rh = (const float*)d_in[8];
    const float* W_s1 = (const float*)d_in[9];
    const float* W_s2 = (const float*)d_in[10];
    const float* W_s3 = (const float*)d_in[11];
    const float* bias = (const float*)d_in[12];
    const float* W_im = (const float*)d_in[13];
    const float* W_hm = (const float*)d_in[14];
    const float* fc1_w = (const float*)d_in[15];
    const float* fc1_b = (const float*)d_in[16];
    const float* W_im1 = (const float*)d_in[17];
    const float* W_hm1 = (const float*)d_in[18];
    const float* W_mm1 = (const float*)d_in[19];
    const float* bias_m1 = (const float*)d_in[20];
    const float* bias_1 = (const float*)d_in[21];
    const float* bias_2 = (const float*)d_in[22];
    const float* bias_3 = (const float*)d_in[23];
    float* out = (float*)d_out;

    float* ws = (float*)d_ws;
    float* read_head = ws;                  // 256*129 = 33024
    float* head1 = read_head + 33024;       // 33024
    float* v1 = head1 + 33024;              // 262144
    float* v2 = v1 + 262144;                // 262144
    float* c1 = v2 + 262144;                // 256
    float* c2 = c1 + 256;                   // 256
    float* sg1 = c2 + 256;                  // 65536
    float* sg2 = sg1 + 65536;               // 65536
    float* entry = sg2 + 65536;             // 262144
    float* wb = entry + 262144;             // 786432
    float* S = wb + 786432;                 // 786432

    k_heads<<<BB, 256, 0, stream>>>(input_, h0, W_im, W_hm, read_head);
    k_project<<<BB, 256, 0, stream>>>(read_head, fc1_w, fc1_b, v1, c1);
    k_scores<<<dim3(BB, 8), 256, 0, stream>>>(mem, h0, v1, c1, read_head, last_usage, u1, sg1);
    k_sel1<<<BB, 256, 0, stream>>>(sg1, mem, h0, input_, W_im1, W_hm1, W_mm1, bias_m1,
                                   fc1_w, fc1_b, entry, head1, v2, c2);
    k_scores<<<dim3(BB, 8), 256, 0, stream>>>(mem, h0, v2, c2, head1, last_usage, u2, sg2);
    k_sel2<<<BB, 256, 0, stream>>>(sg2, mem, h0, out + (size_t)BB * HH);
    k_gemm_gru<<<dim3(48, 4), 256, 0, stream>>>(input_, h0, entry, W_ih, W_hh, W_rh, bias, wb);
    k_gemm_s<<<dim3(48, 4), 256, 0, stream>>>(input_, h0, entry, W_s1, W_s2, W_s3,
                                              bias_1, bias_2, bias_3, S);
    k_final<<<(BB * HH) / 256, 256, 0, stream>>>(wb, S, h0, out);
}

// Round 3
// 838.902 us; speedup vs baseline: 1.7369x; 1.7369x over previous
//
#include <hip/hip_runtime.h>

#define BB 256
#define HH 1024
#define MM 256
#define HS 128
#define NH 129  // HS+1

typedef __attribute__((ext_vector_type(8))) short short8;
typedef __attribute__((ext_vector_type(4))) float float4v;

__device__ __forceinline__ float sigmoidf_(float x) { return 1.0f / (1.0f + expf(-x)); }
__device__ __forceinline__ float gumbelf_(float u) { return -logf(1e-20f - logf(1e-20f + u)); }

// fp32 -> bf16 round-to-nearest-even
__device__ __forceinline__ unsigned short f2bf(float x) {
    union { float f; unsigned u; } c; c.f = x;
    unsigned u = c.u;
    return (unsigned short)((u + 0x7FFFu + ((u >> 16) & 1u)) >> 16);
}

// ---------------------------------------------------------------- small ops

// read_head = tanh(input_ @ W_im + h_0 @ W_hm)   (B, NH)
__global__ __launch_bounds__(256) void k_heads(const float* __restrict__ input_,
                                               const float* __restrict__ h0,
                                               const float* __restrict__ W_im,
                                               const float* __restrict__ W_hm,
                                               float* __restrict__ read_head) {
    __shared__ float sx[HH], sh[HH];
    int b = blockIdx.x;
    for (int i = threadIdx.x; i < HH; i += blockDim.x) {
        sx[i] = input_[b * HH + i];
        sh[i] = h0[b * HH + i];
    }
    __syncthreads();
    int j = threadIdx.x;
    if (j < NH) {
        float acc = 0.f;
        for (int h = 0; h < HH; ++h)
            acc += sx[h] * W_im[h * NH + j] + sh[h] * W_hm[h * NH + j];
        read_head[b * NH + j] = tanhf(acc);
    }
}

// v[b,h] = sum_j head[b,j]*fc1_w[j,h]  (j<128);  c[b] = sum_j head[b,j]*fc1_b[j]
__global__ __launch_bounds__(256) void k_project(const float* __restrict__ head,
                                                 const float* __restrict__ fc1_w,
                                                 const float* __restrict__ fc1_b,
                                                 float* __restrict__ v,
                                                 float* __restrict__ c) {
    __shared__ float sj[NH];
    int b = blockIdx.x;
    for (int i = threadIdx.x; i < NH; i += blockDim.x) sj[i] = head[b * NH + i];
    __syncthreads();
    for (int h = threadIdx.x; h < HH; h += blockDim.x) {
        float acc = 0.f;
        for (int j = 0; j < HS; ++j) acc += sj[j] * fc1_w[j * HH + h];
        v[b * HH + h] = acc;
    }
    if (threadIdx.x == 0) {
        float acc = 0.f;
        for (int j = 0; j < HS; ++j) acc += sj[j] * fc1_b[j];
        c[b] = acc;
    }
}

// sg[b,m] = dot(mem_eff[b,m,:], v[b,:]) + c[b] + head[b,128]*sigmoid(last_usage) + gumbel(u)
__global__ __launch_bounds__(256) void k_scores(const float* __restrict__ mem,
                                                const float* __restrict__ h0,
                                                const float* __restrict__ v,
                                                const float* __restrict__ c,
                                                const float* __restrict__ head,
                                                const float* __restrict__ last_usage,
                                                const float* __restrict__ u,
                                                float* __restrict__ sg_out) {
    __shared__ float sv[HH];
    int b = blockIdx.x;
    int mstart = blockIdx.y * 32;
    for (int i = threadIdx.x; i < HH; i += blockDim.x) sv[i] = v[b * HH + i];
    __syncthreads();
    int wave = threadIdx.x >> 6, lane = threadIdx.x & 63;
    for (int i = 0; i < 8; ++i) {
        int m = mstart + wave * 8 + i;
        const float* row = (m == 0) ? (h0 + (size_t)b * HH) : (mem + ((size_t)(b * MM + m)) * HH);
        float p = 0.f;
        for (int h = lane; h < HH; h += 64) p += row[h] * sv[h];
        for (int off = 32; off > 0; off >>= 1) p += __shfl_down(p, off, 64);
        if (lane == 0) {
            float lu = sigmoidf_(last_usage[b * MM + m]);
            float s = p + c[b] + head[b * NH + HS] * lu;
            sg_out[b * MM + m] = s + gumbelf_(u[b * MM + m]);  // TAU = 1
        }
    }
}

// argmax over m, gather entry row; then head1 = tanh(...); then v2, c2
__global__ __launch_bounds__(256) void k_sel1(const float* __restrict__ sg1,
                                              const float* __restrict__ mem,
                                              const float* __restrict__ h0,
                                              const float* __restrict__ input_,
                                              const float* __restrict__ W_im1,
                                              const float* __restrict__ W_hm1,
                                              const float* __restrict__ W_mm1,
                                              const float* __restrict__ bias_m1,
                                              const float* __restrict__ fc1_w,
                                              const float* __restrict__ fc1_b,
                                              float* __restrict__ entry,
                                              float* __restrict__ head1,
                                              float* __restrict__ v2,
                                              float* __restrict__ c2) {
    __shared__ float svals[256];
    __shared__ int sidx[256];
    __shared__ float se[HH], sx[HH], sh[HH];
    __shared__ float sj[NH];
    int b = blockIdx.x, t = threadIdx.x;
    svals[t] = sg1[b * MM + t];
    sidx[t] = t;
    __syncthreads();
    for (int s = 128; s > 0; s >>= 1) {
        if (t < s) {
            if (svals[t + s] > svals[t]) { svals[t] = svals[t + s]; sidx[t] = sidx[t + s]; }
        }
        __syncthreads();
    }
    int mstar = sidx[0];
    const float* row = (mstar == 0) ? (h0 + (size_t)b * HH) : (mem + ((size_t)(b * MM + mstar)) * HH);
    for (int h = t; h < HH; h += 256) {
        float e = row[h];
        se[h] = e;
        entry[b * HH + h] = e;
        sx[h] = input_[b * HH + h];
        sh[h] = h0[b * HH + h];
    }
    __syncthreads();
    if (t < NH) {
        float acc = bias_m1[t];
        for (int h = 0; h < HH; ++h)
            acc += sx[h] * W_im1[h * NH + t] + sh[h] * W_hm1[h * NH + t] + se[h] * W_mm1[h * NH + t];
        float hv = tanhf(acc);
        head1[b * NH + t] = hv;
        sj[t] = hv;
    }
    __syncthreads();
    for (int h = t; h < HH; h += 256) {
        float acc = 0.f;
        for (int j = 0; j < HS; ++j) acc += sj[j] * fc1_w[j * HH + h];
        v2[b * HH + h] = acc;
    }
    if (t == 0) {
        float acc = 0.f;
        for (int j = 0; j < HS; ++j) acc += sj[j] * fc1_b[j];
        c2[b] = acc;
    }
}

// argmax over m for y2, gather entry_o directly into o's second half
__global__ __launch_bounds__(256) void k_sel2(const float* __restrict__ sg2,
                                              const float* __restrict__ mem,
                                              const float* __restrict__ h0,
                                              float* __restrict__ out_o) {
    __shared__ float svals[256];
    __shared__ int sidx[256];
    int b = blockIdx.x, t = threadIdx.x;
    svals[t] = sg2[b * MM + t];
    sidx[t] = t;
    __syncthreads();
    for (int s = 128; s > 0; s >>= 1) {
        if (t < s) {
            if (svals[t + s] > svals[t]) { svals[t] = svals[t + s]; sidx[t] = sidx[t + s]; }
        }
        __syncthreads();
    }
    int mstar = sidx[0];
    const float* row = (mstar == 0) ? (h0 + (size_t)b * HH) : (mem + ((size_t)(b * MM + mstar)) * HH);
    for (int h = t; h < HH; h += 256) out_o[(size_t)b * 2 * HH + HH + h] = row[h];
}

// ---------------------------------------------------------------- conversions

// Abf[m][k] bf16, k: 0..1023 input_, 1024..2047 h0, 2048..3071 entry
__global__ __launch_bounds__(256) void k_cvt_act(const float* __restrict__ input_,
                                                 const float* __restrict__ h0,
                                                 const float* __restrict__ entry,
                                                 unsigned short* __restrict__ Abf) {
    int idx = blockIdx.x * 256 + threadIdx.x;  // 196608 total
    int e0 = idx * 4;
    int m = e0 / 3072;
    int kk = e0 - m * 3072;
    int seg = kk >> 10, kin = kk & 1023;
    const float* src = (seg == 0 ? input_ : seg == 1 ? h0 : entry) + m * 1024 + kin;
    float4 v = *(const float4*)src;
    ushort4 o;
    o.x = f2bf(v.x); o.y = f2bf(v.y); o.z = f2bf(v.z); o.w = f2bf(v.w);
    *(ushort4*)(Abf + e0) = o;
}

// WtG[n][k] = bf16(Wcat[k][n]), Wcat = [W_ih; W_hh; W_rh] (3072 x 3072), stride 3072
__global__ __launch_bounds__(256) void k_cvt_wtG(const float* __restrict__ W_ih,
                                                 const float* __restrict__ W_hh,
                                                 const float* __restrict__ W_rh,
                                                 unsigned short* __restrict__ WtG) {
    __shared__ unsigned short T[64][66];
    int bx = blockIdx.x;  // 48*48 tiles of 64x64
    int kt = bx / 48, nt = bx % 48;
    int k0 = kt * 64, n0 = nt * 64;
    const float* src = (k0 < 1024) ? W_ih : (k0 < 2048) ? W_hh : W_rh;
    int krel = k0 & 1023;
    int t = threadIdx.x;
    for (int i = 0; i < 16; ++i) {
        int e = i * 256 + t;
        int kk = e >> 6, nn = e & 63;
        T[nn][kk] = f2bf(src[(size_t)(krel + kk) * 3072 + n0 + nn]);
    }
    __syncthreads();
    for (int i = 0; i < 8; ++i) {
        int e = i * 256 + t;
        int nn = e >> 5, kk2 = (e & 31) * 2;
        unsigned val = (unsigned)T[nn][kk2] | ((unsigned)T[nn][kk2 + 1] << 16);
        *(unsigned*)(WtG + (size_t)(n0 + nn) * 3072 + k0 + kk2) = val;
    }
}

// WtS[seg][n][k] = bf16(W_s{seg+1}[k][n]), each 1024x1024, stride 1024
__global__ __launch_bounds__(256) void k_cvt_wtS(const float* __restrict__ W_s1,
                                                 const float* __restrict__ W_s2,
                                                 const float* __restrict__ W_s3,
                                                 unsigned short* __restrict__ WtS) {
    __shared__ unsigned short T[64][66];
    int bx = blockIdx.x;  // 3 * 16 * 16
    int seg = bx >> 8;
    int rem = bx & 255;
    int kt = rem >> 4, nt = rem & 15;
    int k0 = kt * 64, n0 = nt * 64;
    const float* src = (seg == 0) ? W_s1 : (seg == 1) ? W_s2 : W_s3;
    unsigned short* dst = WtS + (size_t)seg * 1048576;
    int t = threadIdx.x;
    for (int i = 0; i < 16; ++i) {
        int e = i * 256 + t;
        int kk = e >> 6, nn = e & 63;
        T[nn][kk] = f2bf(src[(size_t)(k0 + kk) * 1024 + n0 + nn]);
    }
    __syncthreads();
    for (int i = 0; i < 8; ++i) {
        int e = i * 256 + t;
        int nn = e >> 5, kk2 = (e & 31) * 2;
        unsigned val = (unsigned)T[nn][kk2] | ((unsigned)T[nn][kk2 + 1] << 16);
        *(unsigned*)(dst + (size_t)(n0 + nn) * 1024 + k0 + kk2) = val;
    }
}

__global__ __launch_bounds__(256) void k_zero(float4* __restrict__ p) {
    p[blockIdx.x * 256 + threadIdx.x] = make_float4(0.f, 0.f, 0.f, 0.f);
}

// ---------------------------------------------------------------- MFMA GEMM
// 192 blocks. Each: C(128x128) = A(128x1024) * B^T-tile, bf16 MFMA 16x16x32.
// units 0..71: wb split-K (atomicAdd into wbacc); units 72..95: S segments (store).
__global__ __launch_bounds__(256) void k_gemm(const unsigned short* __restrict__ Abf,
                                              const unsigned short* __restrict__ WtG,
                                              const unsigned short* __restrict__ WtS,
                                              float* __restrict__ wbacc,
                                              float* __restrict__ S) {
    __shared__ unsigned short As[128 * 72];
    __shared__ unsigned short Bs[128 * 72];
    int bx = blockIdx.x;
    int mtile = bx & 1, unit = bx >> 1;
    int m0 = mtile * 128;
    const unsigned short* Bp;
    int bstr, ksel, ncol0;
    bool iswb;
    if (unit < 72) {
        iswb = true;
        int nt = unit % 24;
        ksel = unit / 24;
        ncol0 = nt * 128;
        Bp = WtG + (size_t)ncol0 * 3072 + ksel * 1024;
        bstr = 3072;
    } else {
        iswb = false;
        int su = unit - 72;
        int seg = su >> 3, nts = su & 7;
        ksel = seg;
        ncol0 = seg * 1024 + nts * 128;
        Bp = WtS + (size_t)seg * 1048576 + (size_t)(nts * 128) * 1024;
        bstr = 1024;
    }
    const unsigned short* Ap = Abf + ksel * 1024;

    int tid = threadIdx.x;
    int wave = tid >> 6, lane = tid & 63;
    int wm = wave >> 1, wn = wave & 1;
    int q = lane >> 4, lm = lane & 15;

    float4v acc[4][4];
    for (int i = 0; i < 4; ++i)
        for (int j = 0; j < 4; ++j)
            acc[i][j] = (float4v){0.f, 0.f, 0.f, 0.f};

    for (int kt = 0; kt < 1024; kt += 64) {
        for (int rr = 0; rr < 4; ++rr) {
            int e = rr * 256 + tid;
            int row = e >> 3, cg = e & 7;
            *(uint4*)&As[row * 72 + cg * 8] =
                *(const uint4*)(Ap + (size_t)(m0 + row) * 3072 + kt + cg * 8);
            *(uint4*)&Bs[row * 72 + cg * 8] =
                *(const uint4*)(Bp + (size_t)row * bstr + kt + cg * 8);
        }
        __syncthreads();
        for (int ks = 0; ks < 64; ks += 32) {
            short8 av[4], bv[4];
            for (int i = 0; i < 4; ++i)
                av[i] = *(const short8*)&As[(wm * 64 + i * 16 + lm) * 72 + ks + q * 8];
            for (int j = 0; j < 4; ++j)
                bv[j] = *(const short8*)&Bs[(wn * 64 + j * 16 + lm) * 72 + ks + q * 8];
            for (int i = 0; i < 4; ++i)
                for (int j = 0; j < 4; ++j)
                    acc[i][j] = __builtin_amdgcn_mfma_f32_16x16x32_bf16(av[i], bv[j], acc[i][j], 0, 0, 0);
        }
        __syncthreads();
    }

    for (int i = 0; i < 4; ++i)
        for (int j = 0; j < 4; ++j) {
            int n = ncol0 + wn * 64 + j * 16 + lm;
            for (int reg = 0; reg < 4; ++reg) {
                int m = m0 + wm * 64 + i * 16 + q * 4 + reg;
                float val = acc[i][j][reg];
                if (iswb) atomicAdd(&wbacc[(size_t)m * 3072 + n], val);
                else S[(size_t)m * 3072 + n] = val;
            }
        }
}

// ---------------------------------------------------------------- epilogue
__global__ __launch_bounds__(256) void k_final(const float* __restrict__ wbacc,
                                               const float* __restrict__ S,
                                               const float* __restrict__ h0,
                                               const float* __restrict__ bias,
                                               const float* __restrict__ b1,
                                               const float* __restrict__ b2,
                                               const float* __restrict__ b3,
                                               float* __restrict__ out) {
    int idx = blockIdx.x * 256 + threadIdx.x;
    int b = idx >> 10, h = idx & 1023;
    float r = sigmoidf_(wbacc[(size_t)b * 3072 + h] + bias[h]);
    float z = sigmoidf_(wbacc[(size_t)b * 3072 + 1024 + h] + bias[1024 + h]);
    float n = sigmoidf_(wbacc[(size_t)b * 3072 + 2048 + h] + bias[2048 + h]);
    float s1 = S[(size_t)b * 3072 + h] + b1[h];
    float s2 = S[(size_t)b * 3072 + 1024 + h] + b2[h];
    float s3 = S[(size_t)b * 3072 + 2048 + h] + b3[h];
    float hn = tanhf(s1 + r * s2 + z * s3);
    float h1 = n * hn + (1.f - n) * h0[idx];
    out[idx] = h1;
    out[(size_t)BB * HH + (size_t)b * 2 * HH + h] = h1;
}

extern "C" void kernel_launch(void* const* d_in, const int* in_sizes, int n_in,
                              void* d_out, int out_size, void* d_ws, size_t ws_size,
                              hipStream_t stream) {
    const float* input_ = (const float*)d_in[0];
    const float* h0 = (const float*)d_in[1];
    const float* mem = (const float*)d_in[2];
    const float* last_usage = (const float*)d_in[3];
    const float* u1 = (const float*)d_in[4];
    const float* u2 = (const float*)d_in[5];
    const float* W_ih = (const float*)d_in[6];
    const float* W_hh = (const float*)d_in[7];
    const float* W_rh = (const float*)d_in[8];
    const float* W_s1 = (const float*)d_in[9];
    const float* W_s2 = (const float*)d_in[10];
    const float* W_s3 = (const float*)d_in[11];
    const float* bias = (const float*)d_in[12];
    const float* W_im = (const float*)d_in[13];
    const float* W_hm = (const float*)d_in[14];
    const float* fc1_w = (const float*)d_in[15];
    const float* fc1_b = (const float*)d_in[16];
    const float* W_im1 = (const float*)d_in[17];
    const float* W_hm1 = (const float*)d_in[18];
    const float* W_mm1 = (const float*)d_in[19];
    const float* bias_m1 = (const float*)d_in[20];
    const float* bias_1 = (const float*)d_in[21];
    const float* bias_2 = (const float*)d_in[22];
    const float* bias_3 = (const float*)d_in[23];
    float* out = (float*)d_out;

    float* ws = (float*)d_ws;
    float* read_head = ws;                  // 33024
    float* head1 = read_head + 33024;       // 33024
    float* v1 = head1 + 33024;              // 262144
    float* v2 = v1 + 262144;                // 262144
    float* c1 = v2 + 262144;                // 256
    float* c2 = c1 + 256;                   // 256
    float* sg1 = c2 + 256;                  // 65536
    float* sg2 = sg1 + 65536;               // 65536
    float* entry = sg2 + 65536;             // 262144
    float* wbacc = entry + 262144;          // 786432
    float* S = wbacc + 786432;              // 786432
    unsigned short* Abf = (unsigned short*)(S + 786432);  // 786432 bf16
    unsigned short* WtG = Abf + 786432;     // 9437184 bf16
    unsigned short* WtS = WtG + 9437184;    // 3145728 bf16

    k_cvt_wtG<<<2304, 256, 0, stream>>>(W_ih, W_hh, W_rh, WtG);
    k_cvt_wtS<<<768, 256, 0, stream>>>(W_s1, W_s2, W_s3, WtS);
    k_zero<<<768, 256, 0, stream>>>((float4*)wbacc);
    k_heads<<<BB, 256, 0, stream>>>(input_, h0, W_im, W_hm, read_head);
    k_project<<<BB, 256, 0, stream>>>(read_head, fc1_w, fc1_b, v1, c1);
    k_scores<<<dim3(BB, 8), 256, 0, stream>>>(mem, h0, v1, c1, read_head, last_usage, u1, sg1);
    k_sel1<<<BB, 256, 0, stream>>>(sg1, mem, h0, input_, W_im1, W_hm1, W_mm1, bias_m1,
                                   fc1_w, fc1_b, entry, head1, v2, c2);
    k_cvt_act<<<768, 256, 0, stream>>>(input_, h0, entry, Abf);
    k_scores<<<dim3(BB, 8), 256, 0, stream>>>(mem, h0, v2, c2, head1, last_usage, u2, sg2);
    k_sel2<<<BB, 256, 0, stream>>>(sg2, mem, h0, out + (size_t)BB * HH);
    k_gemm<<<192, 256, 0, stream>>>(Abf, WtG, WtS, wbacc, S);
    k_final<<<(BB * HH) / 256, 256, 0, stream>>>(wbacc, S, h0, bias, bias_1, bias_2, bias_3, out);
}

// Round 4
// 701.850 us; speedup vs baseline: 2.0760x; 1.1953x over previous
//
#include <hip/hip_runtime.h>

#define BB 256
#define HH 1024
#define MM 256
#define HS 128
#define NH 129  // HS+1

typedef __attribute__((ext_vector_type(8))) short short8;
typedef __attribute__((ext_vector_type(4))) float float4v;

__device__ __forceinline__ float sigmoidf_(float x) { return 1.0f / (1.0f + expf(-x)); }
__device__ __forceinline__ float gumbelf_(float u) { return -logf(1e-20f - logf(1e-20f + u)); }

__device__ __forceinline__ unsigned short f2bf(float x) {
    union { float f; unsigned u; } c; c.f = x;
    unsigned u = c.u;
    return (unsigned short)((u + 0x7FFFu + ((u >> 16) & 1u)) >> 16);
}

// ---------------------------------------------------------------- fused heads+project
// read_head = tanh(input_@W_im + h0@W_hm); v1 = read_head[:128]@fc1_w; c1 = read_head[:128]@fc1_b
__global__ __launch_bounds__(256) void k_heads_project(const float* __restrict__ input_,
                                                       const float* __restrict__ h0,
                                                       const float* __restrict__ W_im,
                                                       const float* __restrict__ W_hm,
                                                       const float* __restrict__ fc1_w,
                                                       const float* __restrict__ fc1_b,
                                                       float* __restrict__ read_head,
                                                       float* __restrict__ v,
                                                       float* __restrict__ c) {
    __shared__ float sx[HH], sh[HH];
    __shared__ float sj[NH];
    int b = blockIdx.x, t = threadIdx.x;
    for (int i = t; i < HH / 4; i += 256) {
        ((float4*)sx)[i] = ((const float4*)(input_ + (size_t)b * HH))[i];
        ((float4*)sh)[i] = ((const float4*)(h0 + (size_t)b * HH))[i];
    }
    __syncthreads();
    if (t < NH) {
        float acc = 0.f;
#pragma unroll 8
        for (int h = 0; h < HH; ++h)
            acc += sx[h] * W_im[h * NH + t] + sh[h] * W_hm[h * NH + t];
        float tv = tanhf(acc);
        read_head[b * NH + t] = tv;
        sj[t] = tv;
    }
    __syncthreads();
    {
        int hb = t * 4;
        float4 a = make_float4(0.f, 0.f, 0.f, 0.f);
#pragma unroll 4
        for (int j = 0; j < HS; ++j) {
            float s = sj[j];
            float4 w = *(const float4*)(fc1_w + (size_t)j * HH + hb);
            a.x += s * w.x; a.y += s * w.y; a.z += s * w.z; a.w += s * w.w;
        }
        *(float4*)(v + (size_t)b * HH + hb) = a;
    }
    if (t == 0) {
        float acc = 0.f;
        for (int j = 0; j < HS; ++j) acc += sj[j] * fc1_b[j];
        c[b] = acc;
    }
}

// ---------------------------------------------------------------- scores (float4)
__global__ __launch_bounds__(256) void k_scores(const float* __restrict__ mem,
                                                const float* __restrict__ h0,
                                                const float* __restrict__ v,
                                                const float* __restrict__ c,
                                                const float* __restrict__ head,
                                                const float* __restrict__ last_usage,
                                                const float* __restrict__ u,
                                                float* __restrict__ sg_out) {
    int b = blockIdx.x;
    int wave = threadIdx.x >> 6, lane = threadIdx.x & 63;
    int mstart = blockIdx.y * 32 + wave * 8;
    float4 rv[4];
#pragma unroll
    for (int it = 0; it < 4; ++it)
        rv[it] = *(const float4*)(v + (size_t)b * HH + it * 256 + lane * 4);
    float cb = c[b];
    float hf = head[b * NH + HS];
    for (int i = 0; i < 8; ++i) {
        int m = mstart + i;
        const float* row = (m == 0) ? (h0 + (size_t)b * HH) : (mem + ((size_t)(b * MM + m)) * HH);
        float p = 0.f;
#pragma unroll
        for (int it = 0; it < 4; ++it) {
            float4 mv = *(const float4*)(row + it * 256 + lane * 4);
            p += mv.x * rv[it].x + mv.y * rv[it].y + mv.z * rv[it].z + mv.w * rv[it].w;
        }
        for (int off = 32; off > 0; off >>= 1) p += __shfl_down(p, off, 64);
        if (lane == 0) {
            float lu = sigmoidf_(last_usage[b * MM + m]);
            sg_out[b * MM + m] = p + cb + hf * lu + gumbelf_(u[b * MM + m]);
        }
    }
}

// ---------------------------------------------------------------- sel1
__global__ __launch_bounds__(256) void k_sel1(const float* __restrict__ sg1,
                                              const float* __restrict__ mem,
                                              const float* __restrict__ h0,
                                              const float* __restrict__ input_,
                                              const float* __restrict__ W_im1,
                                              const float* __restrict__ W_hm1,
                                              const float* __restrict__ W_mm1,
                                              const float* __restrict__ bias_m1,
                                              const float* __restrict__ fc1_w,
                                              const float* __restrict__ fc1_b,
                                              float* __restrict__ entry,
                                              float* __restrict__ head1,
                                              float* __restrict__ v2,
                                              float* __restrict__ c2) {
    __shared__ float svals[256];
    __shared__ int sidx[256];
    __shared__ float se[HH], sx[HH], sh[HH];
    __shared__ float sj[NH];
    int b = blockIdx.x, t = threadIdx.x;
    svals[t] = sg1[b * MM + t];
    sidx[t] = t;
    __syncthreads();
    for (int s = 128; s > 0; s >>= 1) {
        if (t < s) {
            if (svals[t + s] > svals[t]) { svals[t] = svals[t + s]; sidx[t] = sidx[t + s]; }
        }
        __syncthreads();
    }
    int mstar = sidx[0];
    const float* row = (mstar == 0) ? (h0 + (size_t)b * HH) : (mem + ((size_t)(b * MM + mstar)) * HH);
    {
        int hb = t * 4;
        float4 e = *(const float4*)(row + hb);
        *(float4*)(se + hb) = e;
        *(float4*)(entry + (size_t)b * HH + hb) = e;
        *(float4*)(sx + hb) = *(const float4*)(input_ + (size_t)b * HH + hb);
        *(float4*)(sh + hb) = *(const float4*)(h0 + (size_t)b * HH + hb);
    }
    __syncthreads();
    if (t < NH) {
        float acc = bias_m1[t];
#pragma unroll 8
        for (int h = 0; h < HH; ++h)
            acc += sx[h] * W_im1[h * NH + t] + sh[h] * W_hm1[h * NH + t] + se[h] * W_mm1[h * NH + t];
        float hv = tanhf(acc);
        head1[b * NH + t] = hv;
        sj[t] = hv;
    }
    __syncthreads();
    {
        int hb = t * 4;
        float4 a = make_float4(0.f, 0.f, 0.f, 0.f);
#pragma unroll 4
        for (int j = 0; j < HS; ++j) {
            float s = sj[j];
            float4 w = *(const float4*)(fc1_w + (size_t)j * HH + hb);
            a.x += s * w.x; a.y += s * w.y; a.z += s * w.z; a.w += s * w.w;
        }
        *(float4*)(v2 + (size_t)b * HH + hb) = a;
    }
    if (t == 0) {
        float acc = 0.f;
        for (int j = 0; j < HS; ++j) acc += sj[j] * fc1_b[j];
        c2[b] = acc;
    }
}

// ---------------------------------------------------------------- conversions
__global__ __launch_bounds__(256) void k_cvt_act(const float* __restrict__ input_,
                                                 const float* __restrict__ h0,
                                                 const float* __restrict__ entry,
                                                 unsigned short* __restrict__ Abf) {
    int idx = blockIdx.x * 256 + threadIdx.x;
    int e0 = idx * 4;
    int m = e0 / 3072;
    int kk = e0 - m * 3072;
    int seg = kk >> 10, kin = kk & 1023;
    const float* src = (seg == 0 ? input_ : seg == 1 ? h0 : entry) + m * 1024 + kin;
    float4 v = *(const float4*)src;
    ushort4 o;
    o.x = f2bf(v.x); o.y = f2bf(v.y); o.z = f2bf(v.z); o.w = f2bf(v.w);
    *(ushort4*)(Abf + e0) = o;
}

// merged weight transpose+convert: blocks 0..2303 -> WtG, 2304..3071 -> WtS
__global__ __launch_bounds__(256) void k_cvt_w(const float* __restrict__ W_ih,
                                               const float* __restrict__ W_hh,
                                               const float* __restrict__ W_rh,
                                               const float* __restrict__ W_s1,
                                               const float* __restrict__ W_s2,
                                               const float* __restrict__ W_s3,
                                               unsigned short* __restrict__ WtG,
                                               unsigned short* __restrict__ WtS) {
    __shared__ unsigned short T[64][66];
    int bx = blockIdx.x;
    const float* src;
    unsigned short* dst;
    int k0, n0, sstr, dstr, krel;
    if (bx < 2304) {
        int kt = bx / 48, nt = bx % 48;
        k0 = kt * 64; n0 = nt * 64;
        src = (k0 < 1024) ? W_ih : (k0 < 2048) ? W_hh : W_rh;
        krel = k0 & 1023;
        dst = WtG; sstr = 3072; dstr = 3072;
    } else {
        int r = bx - 2304;
        int seg = r >> 8;
        int rem = r & 255;
        int kt = rem >> 4, nt = rem & 15;
        k0 = kt * 64; n0 = nt * 64;
        src = (seg == 0) ? W_s1 : (seg == 1) ? W_s2 : W_s3;
        krel = k0;
        dst = WtS + (size_t)seg * 1048576; sstr = 1024; dstr = 1024;
    }
    int t = threadIdx.x;
    for (int i = 0; i < 16; ++i) {
        int e = i * 256 + t;
        int kk = e >> 6, nn = e & 63;
        T[nn][kk] = f2bf(src[(size_t)(krel + kk) * sstr + n0 + nn]);
    }
    __syncthreads();
    for (int i = 0; i < 8; ++i) {
        int e = i * 256 + t;
        int nn = e >> 5, kk2 = (e & 31) * 2;
        unsigned val = (unsigned)T[nn][kk2] | ((unsigned)T[nn][kk2 + 1] << 16);
        *(unsigned*)(dst + (size_t)(n0 + nn) * dstr + k0 + kk2) = val;
    }
}

// ---------------------------------------------------------------- MFMA GEMM
// 192 blocks; units 0..71: wb split-K -> wbp[ksel]; units 72..95: S segments.
__global__ __launch_bounds__(256) void k_gemm(const unsigned short* __restrict__ Abf,
                                              const unsigned short* __restrict__ WtG,
                                              const unsigned short* __restrict__ WtS,
                                              float* __restrict__ wbp,
                                              float* __restrict__ S) {
    __shared__ unsigned short As[128 * 72];
    __shared__ unsigned short Bs[128 * 72];
    int bx = blockIdx.x;
    int mtile = bx & 1, unit = bx >> 1;
    int m0 = mtile * 128;
    const unsigned short* Bp;
    int bstr, ksel, ncol0;
    bool iswb;
    if (unit < 72) {
        iswb = true;
        int nt = unit % 24;
        ksel = unit / 24;
        ncol0 = nt * 128;
        Bp = WtG + (size_t)ncol0 * 3072 + ksel * 1024;
        bstr = 3072;
    } else {
        iswb = false;
        int su = unit - 72;
        int seg = su >> 3, nts = su & 7;
        ksel = seg;
        ncol0 = seg * 1024 + nts * 128;
        Bp = WtS + (size_t)seg * 1048576 + (size_t)(nts * 128) * 1024;
        bstr = 1024;
    }
    const unsigned short* Ap = Abf + ksel * 1024;

    int tid = threadIdx.x;
    int wave = tid >> 6, lane = tid & 63;
    int wm = wave >> 1, wn = wave & 1;
    int q = lane >> 4, lm = lane & 15;

    float4v acc[4][4];
    for (int i = 0; i < 4; ++i)
        for (int j = 0; j < 4; ++j)
            acc[i][j] = (float4v){0.f, 0.f, 0.f, 0.f};

    for (int kt = 0; kt < 1024; kt += 64) {
        for (int rr = 0; rr < 4; ++rr) {
            int e = rr * 256 + tid;
            int row = e >> 3, cg = e & 7;
            *(uint4*)&As[row * 72 + cg * 8] =
                *(const uint4*)(Ap + (size_t)(m0 + row) * 3072 + kt + cg * 8);
            *(uint4*)&Bs[row * 72 + cg * 8] =
                *(const uint4*)(Bp + (size_t)row * bstr + kt + cg * 8);
        }
        __syncthreads();
        for (int ks = 0; ks < 64; ks += 32) {
            short8 av[4], bv[4];
            for (int i = 0; i < 4; ++i)
                av[i] = *(const short8*)&As[(wm * 64 + i * 16 + lm) * 72 + ks + q * 8];
            for (int j = 0; j < 4; ++j)
                bv[j] = *(const short8*)&Bs[(wn * 64 + j * 16 + lm) * 72 + ks + q * 8];
            for (int i = 0; i < 4; ++i)
                for (int j = 0; j < 4; ++j)
                    acc[i][j] = __builtin_amdgcn_mfma_f32_16x16x32_bf16(av[i], bv[j], acc[i][j], 0, 0, 0);
        }
        __syncthreads();
    }

    for (int i = 0; i < 4; ++i)
        for (int j = 0; j < 4; ++j) {
            int n = ncol0 + wn * 64 + j * 16 + lm;
            for (int reg = 0; reg < 4; ++reg) {
                int m = m0 + wm * 64 + i * 16 + q * 4 + reg;
                float val = acc[i][j][reg];
                if (iswb) wbp[(size_t)ksel * 786432 + (size_t)m * 3072 + n] = val;
                else S[(size_t)m * 3072 + n] = val;
            }
        }
}

// ---------------------------------------------------------------- final (fused sel2 + GRU epilogue)
__global__ __launch_bounds__(256) void k_final(const float* __restrict__ sg2,
                                               const float* __restrict__ mem,
                                               const float* __restrict__ wbp,
                                               const float* __restrict__ S,
                                               const float* __restrict__ h0,
                                               const float* __restrict__ bias,
                                               const float* __restrict__ b1,
                                               const float* __restrict__ b2,
                                               const float* __restrict__ b3,
                                               float* __restrict__ out) {
    __shared__ float svals[256];
    __shared__ int sidx[256];
    int b = blockIdx.x, t = threadIdx.x;
    svals[t] = sg2[b * MM + t];
    sidx[t] = t;
    __syncthreads();
    for (int s = 128; s > 0; s >>= 1) {
        if (t < s) {
            if (svals[t + s] > svals[t]) { svals[t] = svals[t + s]; sidx[t] = sidx[t + s]; }
        }
        __syncthreads();
    }
    int mstar = sidx[0];
    const float* erow = (mstar == 0) ? (h0 + (size_t)b * HH) : (mem + ((size_t)(b * MM + mstar)) * HH);
    float* o_row = out + (size_t)BB * HH + (size_t)b * 2 * HH;
    {
        int hb = t * 4;
        *(float4*)(o_row + HH + hb) = *(const float4*)(erow + hb);
    }
    int h = t * 4;
    const float* p0 = wbp + (size_t)b * 3072;
    const float* p1 = wbp + 786432 + (size_t)b * 3072;
    const float* p2 = wbp + 2 * 786432 + (size_t)b * 3072;
    const float* Sp = S + (size_t)b * 3072;
    float4 w0 = *(const float4*)(p0 + h);
    float4 w1 = *(const float4*)(p1 + h);
    float4 w2 = *(const float4*)(p2 + h);
    float4 bi = *(const float4*)(bias + h);
    float4 r4 = make_float4(sigmoidf_(w0.x + w1.x + w2.x + bi.x), sigmoidf_(w0.y + w1.y + w2.y + bi.y),
                            sigmoidf_(w0.z + w1.z + w2.z + bi.z), sigmoidf_(w0.w + w1.w + w2.w + bi.w));
    w0 = *(const float4*)(p0 + 1024 + h);
    w1 = *(const float4*)(p1 + 1024 + h);
    w2 = *(const float4*)(p2 + 1024 + h);
    bi = *(const float4*)(bias + 1024 + h);
    float4 z4 = make_float4(sigmoidf_(w0.x + w1.x + w2.x + bi.x), sigmoidf_(w0.y + w1.y + w2.y + bi.y),
                            sigmoidf_(w0.z + w1.z + w2.z + bi.z), sigmoidf_(w0.w + w1.w + w2.w + bi.w));
    w0 = *(const float4*)(p0 + 2048 + h);
    w1 = *(const float4*)(p1 + 2048 + h);
    w2 = *(const float4*)(p2 + 2048 + h);
    bi = *(const float4*)(bias + 2048 + h);
    float4 n4 = make_float4(sigmoidf_(w0.x + w1.x + w2.x + bi.x), sigmoidf_(w0.y + w1.y + w2.y + bi.y),
                            sigmoidf_(w0.z + w1.z + w2.z + bi.z), sigmoidf_(w0.w + w1.w + w2.w + bi.w));
    float4 s1 = *(const float4*)(Sp + h);
    float4 s2 = *(const float4*)(Sp + 1024 + h);
    float4 s3 = *(const float4*)(Sp + 2048 + h);
    float4 v1 = *(const float4*)(b1 + h);
    float4 v2 = *(const float4*)(b2 + h);
    float4 v3 = *(const float4*)(b3 + h);
    float4 h0v = *(const float4*)(h0 + (size_t)b * HH + h);
    float4 hn, h1;
    hn.x = tanhf(s1.x + v1.x + r4.x * (s2.x + v2.x) + z4.x * (s3.x + v3.x));
    hn.y = tanhf(s1.y + v1.y + r4.y * (s2.y + v2.y) + z4.y * (s3.y + v3.y));
    hn.z = tanhf(s1.z + v1.z + r4.z * (s2.z + v2.z) + z4.z * (s3.z + v3.z));
    hn.w = tanhf(s1.w + v1.w + r4.w * (s2.w + v2.w) + z4.w * (s3.w + v3.w));
    h1.x = n4.x * hn.x + (1.f - n4.x) * h0v.x;
    h1.y = n4.y * hn.y + (1.f - n4.y) * h0v.y;
    h1.z = n4.z * hn.z + (1.f - n4.z) * h0v.z;
    h1.w = n4.w * hn.w + (1.f - n4.w) * h0v.w;
    *(float4*)(out + (size_t)b * HH + h) = h1;
    *(float4*)(o_row + h) = h1;
}

extern "C" void kernel_launch(void* const* d_in, const int* in_sizes, int n_in,
                              void* d_out, int out_size, void* d_ws, size_t ws_size,
                              hipStream_t stream) {
    const float* input_ = (const float*)d_in[0];
    const float* h0 = (const float*)d_in[1];
    const float* mem = (const float*)d_in[2];
    const float* last_usage = (const float*)d_in[3];
    const float* u1 = (const float*)d_in[4];
    const float* u2 = (const float*)d_in[5];
    const float* W_ih = (const float*)d_in[6];
    const float* W_hh = (const float*)d_in[7];
    const float* W_rh = (const float*)d_in[8];
    const float* W_s1 = (const float*)d_in[9];
    const float* W_s2 = (const float*)d_in[10];
    const float* W_s3 = (const float*)d_in[11];
    const float* bias = (const float*)d_in[12];
    const float* W_im = (const float*)d_in[13];
    const float* W_hm = (const float*)d_in[14];
    const float* fc1_w = (const float*)d_in[15];
    const float* fc1_b = (const float*)d_in[16];
    const float* W_im1 = (const float*)d_in[17];
    const float* W_hm1 = (const float*)d_in[18];
    const float* W_mm1 = (const float*)d_in[19];
    const float* bias_m1 = (const float*)d_in[20];
    const float* bias_1 = (const float*)d_in[21];
    const float* bias_2 = (const float*)d_in[22];
    const float* bias_3 = (const float*)d_in[23];
    float* out = (float*)d_out;

    float* ws = (float*)d_ws;
    float* read_head = ws;                  // 33024
    float* head1 = read_head + 33024;       // 33024
    float* v1 = head1 + 33024;              // 262144
    float* v2 = v1 + 262144;                // 262144
    float* c1 = v2 + 262144;                // 256
    float* c2 = c1 + 256;                   // 256
    float* sg1 = c2 + 256;                  // 65536
    float* sg2 = sg1 + 65536;               // 65536
    float* entry = sg2 + 65536;             // 262144
    float* wbp = entry + 262144;            // 3 * 786432
    float* S = wbp + 3 * 786432;            // 786432
    unsigned short* Abf = (unsigned short*)(S + 786432);  // 786432 bf16
    unsigned short* WtG = Abf + 786432;     // 9437184 bf16
    unsigned short* WtS = WtG + 9437184;    // 3145728 bf16

    k_cvt_w<<<3072, 256, 0, stream>>>(W_ih, W_hh, W_rh, W_s1, W_s2, W_s3, WtG, WtS);
    k_heads_project<<<BB, 256, 0, stream>>>(input_, h0, W_im, W_hm, fc1_w, fc1_b, read_head, v1, c1);
    k_scores<<<dim3(BB, 8), 256, 0, stream>>>(mem, h0, v1, c1, read_head, last_usage, u1, sg1);
    k_sel1<<<BB, 256, 0, stream>>>(sg1, mem, h0, input_, W_im1, W_hm1, W_mm1, bias_m1,
                                   fc1_w, fc1_b, entry, head1, v2, c2);
    k_cvt_act<<<768, 256, 0, stream>>>(input_, h0, entry, Abf);
    k_scores<<<dim3(BB, 8), 256, 0, stream>>>(mem, h0, v2, c2, head1, last_usage, u2, sg2);
    k_gemm<<<192, 256, 0, stream>>>(Abf, WtG, WtS, wbp, S);
    k_final<<<BB, 256, 0, stream>>>(sg2, mem, wbp, S, h0, bias, bias_1, bias_2, bias_3, out);
}

// Round 5
// 595.888 us; speedup vs baseline: 2.4452x; 1.1778x over previous
//
#include <hip/hip_runtime.h>

#define BB 256
#define HH 1024
#define MM 256
#define HS 128
#define NH 129  // HS+1

typedef __attribute__((ext_vector_type(8))) short short8;
typedef __attribute__((ext_vector_type(4))) float float4v;

__device__ __forceinline__ float sigmoidf_(float x) { return 1.0f / (1.0f + expf(-x)); }
__device__ __forceinline__ float gumbelf_(float u) { return -logf(1e-20f - logf(1e-20f + u)); }

__device__ __forceinline__ unsigned short f2bf(float x) {
    union { float f; unsigned u; } c; c.f = x;
    unsigned u = c.u;
    return (unsigned short)((u + 0x7FFFu + ((u >> 16) & 1u)) >> 16);
}

// ---------------------------------------------------------------- weight convert/transpose
// blocks 0..2303 -> WtG[n][k] (3072x3072), 2304..3071 -> WtS[seg][n][k] (3x1024x1024)
__global__ __launch_bounds__(256) void k_cvt_w(const float* __restrict__ W_ih,
                                               const float* __restrict__ W_hh,
                                               const float* __restrict__ W_rh,
                                               const float* __restrict__ W_s1,
                                               const float* __restrict__ W_s2,
                                               const float* __restrict__ W_s3,
                                               unsigned short* __restrict__ WtG,
                                               unsigned short* __restrict__ WtS) {
    __shared__ unsigned short T[64][66];
    int bx = blockIdx.x;
    const float* src;
    unsigned short* dst;
    int k0, n0, sstr, dstr, krel;
    if (bx < 2304) {
        int kt = bx / 48, nt = bx % 48;
        k0 = kt * 64; n0 = nt * 64;
        src = (k0 < 1024) ? W_ih : (k0 < 2048) ? W_hh : W_rh;
        krel = k0 & 1023;
        dst = WtG; sstr = 3072; dstr = 3072;
    } else {
        int r = bx - 2304;
        int seg = r >> 8;
        int rem = r & 255;
        int kt = rem >> 4, nt = rem & 15;
        k0 = kt * 64; n0 = nt * 64;
        src = (seg == 0) ? W_s1 : (seg == 1) ? W_s2 : W_s3;
        krel = k0;
        dst = WtS + (size_t)seg * 1048576; sstr = 1024; dstr = 1024;
    }
    int t = threadIdx.x;
    for (int i = 0; i < 4; ++i) {
        int e = i * 256 + t;           // 0..1023
        int kk = e >> 4, nn0 = (e & 15) * 4;
        float4 v = *(const float4*)(src + (size_t)(krel + kk) * sstr + n0 + nn0);
        T[nn0 + 0][kk] = f2bf(v.x);
        T[nn0 + 1][kk] = f2bf(v.y);
        T[nn0 + 2][kk] = f2bf(v.z);
        T[nn0 + 3][kk] = f2bf(v.w);
    }
    __syncthreads();
    for (int i = 0; i < 8; ++i) {
        int e = i * 256 + t;
        int nn = e >> 5, kk2 = (e & 31) * 2;
        unsigned val = (unsigned)T[nn][kk2] | ((unsigned)T[nn][kk2 + 1] << 16);
        *(unsigned*)(dst + (size_t)(n0 + nn) * dstr + k0 + kk2) = val;
    }
}

// ---------------------------------------------------------------- fused heads+project+scores (pass 1)
// per-block b: read_head GEMV (8-way K-split), v1 projection, then score 256 mem rows.
// Also writes Abf[:,0:2048] = bf16(input_), bf16(h0).
__global__ __launch_bounds__(1024) void k_score1(const float* __restrict__ input_,
                                                 const float* __restrict__ h0,
                                                 const float* __restrict__ W_im,
                                                 const float* __restrict__ W_hm,
                                                 const float* __restrict__ fc1_w,
                                                 const float* __restrict__ fc1_b,
                                                 const float* __restrict__ mem,
                                                 const float* __restrict__ last_usage,
                                                 const float* __restrict__ u1,
                                                 unsigned short* __restrict__ Abf,
                                                 float* __restrict__ sg_out) {
    __shared__ float sx[HH], sh[HH], sv[HH];
    __shared__ float red[8][128];
    __shared__ float red2[8];
    __shared__ float sj[NH];
    __shared__ float scb;
    int b = blockIdx.x, t = threadIdx.x;
    if (t < 256) {
        float4 v = *(const float4*)(input_ + (size_t)b * HH + t * 4);
        *(float4*)(sx + t * 4) = v;
        ushort4 o; o.x = f2bf(v.x); o.y = f2bf(v.y); o.z = f2bf(v.z); o.w = f2bf(v.w);
        *(ushort4*)(Abf + (size_t)b * 3072 + t * 4) = o;
    } else if (t < 512) {
        int tt = t - 256;
        float4 v = *(const float4*)(h0 + (size_t)b * HH + tt * 4);
        *(float4*)(sh + tt * 4) = v;
        ushort4 o; o.x = f2bf(v.x); o.y = f2bf(v.y); o.z = f2bf(v.z); o.w = f2bf(v.w);
        *(ushort4*)(Abf + (size_t)b * 3072 + 1024 + tt * 4) = o;
    }
    __syncthreads();
    {   // read_head GEMV: j = t&127, K-slice = t>>7
        int j = t & 127, ks = t >> 7;
        int hb = ks * 128;
        float p = 0.f;
#pragma unroll 8
        for (int h = hb; h < hb + 128; ++h)
            p += sx[h] * W_im[h * NH + j] + sh[h] * W_hm[h * NH + j];
        red[ks][j] = p;
        if (t >= 1016) {  // j = 128 extra slices
            int k2 = t - 1016;
            int hb2 = k2 * 128;
            float q = 0.f;
#pragma unroll 8
            for (int h = hb2; h < hb2 + 128; ++h)
                q += sx[h] * W_im[h * NH + 128] + sh[h] * W_hm[h * NH + 128];
            red2[k2] = q;
        }
    }
    __syncthreads();
    if (t < 128) {
        float s = 0.f;
        for (int k = 0; k < 8; ++k) s += red[k][t];
        sj[t] = tanhf(s);
    } else if (t == 128) {
        float s = 0.f;
        for (int k = 0; k < 8; ++k) s += red2[k];
        sj[128] = tanhf(s);
    }
    __syncthreads();
    {   // v projection: thread t computes sv[t]
        float acc = 0.f;
#pragma unroll 4
        for (int j = 0; j < HS; ++j) acc += sj[j] * fc1_w[(size_t)j * HH + t];
        sv[t] = acc;
    }
    if (t < 64) {
        float p = sj[t] * fc1_b[t] + sj[t + 64] * fc1_b[t + 64];
        for (int off = 32; off > 0; off >>= 1) p += __shfl_down(p, off, 64);
        if (t == 0) scb = p;
    }
    __syncthreads();
    float cb = scb, hf = sj[128];
    int wave = t >> 6, lane = t & 63;
    float4 rv[4];
#pragma unroll
    for (int it = 0; it < 4; ++it) rv[it] = *(const float4*)(sv + it * 256 + lane * 4);
    for (int i = 0; i < 16; ++i) {
        int m = wave * 16 + i;
        const float* row = (m == 0) ? (h0 + (size_t)b * HH) : (mem + ((size_t)(b * MM + m)) * HH);
        float p = 0.f;
#pragma unroll
        for (int it = 0; it < 4; ++it) {
            float4 mv = *(const float4*)(row + it * 256 + lane * 4);
            p += mv.x * rv[it].x + mv.y * rv[it].y + mv.z * rv[it].z + mv.w * rv[it].w;
        }
        for (int off = 32; off > 0; off >>= 1) p += __shfl_down(p, off, 64);
        if (lane == 0) {
            float lu = sigmoidf_(last_usage[b * MM + m]);
            sg_out[b * MM + m] = p + cb + hf * lu + gumbelf_(u1[b * MM + m]);
        }
    }
}

// ---------------------------------------------------------------- fused sel1+head1+scores (pass 2)
// argmax(sg1) -> entry (LDS + bf16 to Abf[:,2048:]); head1 GEMV; v2; score -> sg2
__global__ __launch_bounds__(1024) void k_sel_score2(const float* __restrict__ sg1,
                                                     const float* __restrict__ mem,
                                                     const float* __restrict__ h0,
                                                     const float* __restrict__ input_,
                                                     const float* __restrict__ W_im1,
                                                     const float* __restrict__ W_hm1,
                                                     const float* __restrict__ W_mm1,
                                                     const float* __restrict__ bias_m1,
                                                     const float* __restrict__ fc1_w,
                                                     const float* __restrict__ fc1_b,
                                                     const float* __restrict__ last_usage,
                                                     const float* __restrict__ u2,
                                                     unsigned short* __restrict__ Abf,
                                                     float* __restrict__ sg_out) {
    __shared__ float svals[256];
    __shared__ int sidx[256];
    __shared__ float sx[HH], sh[HH], se[HH], sv[HH];
    __shared__ float red[8][128];
    __shared__ float red2[8];
    __shared__ float sj[NH];
    __shared__ float scb;
    int b = blockIdx.x, t = threadIdx.x;
    if (t < 256) {
        svals[t] = sg1[b * MM + t];
        sidx[t] = t;
    }
    __syncthreads();
    for (int s = 128; s > 0; s >>= 1) {
        if (t < s) {
            if (svals[t + s] > svals[t]) { svals[t] = svals[t + s]; sidx[t] = sidx[t + s]; }
        }
        __syncthreads();
    }
    int mstar = sidx[0];
    const float* erow = (mstar == 0) ? (h0 + (size_t)b * HH) : (mem + ((size_t)(b * MM + mstar)) * HH);
    if (t < 256) {
        float4 v = *(const float4*)(erow + t * 4);
        *(float4*)(se + t * 4) = v;
        ushort4 o; o.x = f2bf(v.x); o.y = f2bf(v.y); o.z = f2bf(v.z); o.w = f2bf(v.w);
        *(ushort4*)(Abf + (size_t)b * 3072 + 2048 + t * 4) = o;
    } else if (t < 512) {
        int tt = t - 256;
        *(float4*)(sx + tt * 4) = *(const float4*)(input_ + (size_t)b * HH + tt * 4);
    } else if (t < 768) {
        int tt = t - 512;
        *(float4*)(sh + tt * 4) = *(const float4*)(h0 + (size_t)b * HH + tt * 4);
    }
    __syncthreads();
    {
        int j = t & 127, ks = t >> 7;
        int hb = ks * 128;
        float p = 0.f;
#pragma unroll 4
        for (int h = hb; h < hb + 128; ++h)
            p += sx[h] * W_im1[h * NH + j] + sh[h] * W_hm1[h * NH + j] + se[h] * W_mm1[h * NH + j];
        red[ks][j] = p;
        if (t >= 1016) {
            int k2 = t - 1016;
            int hb2 = k2 * 128;
            float q = 0.f;
#pragma unroll 4
            for (int h = hb2; h < hb2 + 128; ++h)
                q += sx[h] * W_im1[h * NH + 128] + sh[h] * W_hm1[h * NH + 128] + se[h] * W_mm1[h * NH + 128];
            red2[k2] = q;
        }
    }
    __syncthreads();
    if (t < 128) {
        float s = bias_m1[t];
        for (int k = 0; k < 8; ++k) s += red[k][t];
        sj[t] = tanhf(s);
    } else if (t == 128) {
        float s = bias_m1[128];
        for (int k = 0; k < 8; ++k) s += red2[k];
        sj[128] = tanhf(s);
    }
    __syncthreads();
    {
        float acc = 0.f;
#pragma unroll 4
        for (int j = 0; j < HS; ++j) acc += sj[j] * fc1_w[(size_t)j * HH + t];
        sv[t] = acc;
    }
    if (t < 64) {
        float p = sj[t] * fc1_b[t] + sj[t + 64] * fc1_b[t + 64];
        for (int off = 32; off > 0; off >>= 1) p += __shfl_down(p, off, 64);
        if (t == 0) scb = p;
    }
    __syncthreads();
    float cb = scb, hf = sj[128];
    int wave = t >> 6, lane = t & 63;
    float4 rv[4];
#pragma unroll
    for (int it = 0; it < 4; ++it) rv[it] = *(const float4*)(sv + it * 256 + lane * 4);
    for (int i = 0; i < 16; ++i) {
        int m = wave * 16 + i;
        const float* row = (m == 0) ? (h0 + (size_t)b * HH) : (mem + ((size_t)(b * MM + m)) * HH);
        float p = 0.f;
#pragma unroll
        for (int it = 0; it < 4; ++it) {
            float4 mv = *(const float4*)(row + it * 256 + lane * 4);
            p += mv.x * rv[it].x + mv.y * rv[it].y + mv.z * rv[it].z + mv.w * rv[it].w;
        }
        for (int off = 32; off > 0; off >>= 1) p += __shfl_down(p, off, 64);
        if (lane == 0) {
            float lu = sigmoidf_(last_usage[b * MM + m]);
            sg_out[b * MM + m] = p + cb + hf * lu + gumbelf_(u2[b * MM + m]);
        }
    }
}

// ---------------------------------------------------------------- MFMA GEMM (split-K 512)
// 384 blocks = 2 mtiles x 192 units. units 0..143: wb (nt 0..23, kidx 0..5 = ksel*2+khalf)
// units 144..191: S (seg, khalf, nts)
__global__ __launch_bounds__(256) void k_gemm(const unsigned short* __restrict__ Abf,
                                              const unsigned short* __restrict__ WtG,
                                              const unsigned short* __restrict__ WtS,
                                              float* __restrict__ wbp,
                                              float* __restrict__ Sp) {
    __shared__ unsigned short As[128 * 72];
    __shared__ unsigned short Bs[128 * 72];
    int bx = blockIdx.x;
    int mtile = bx & 1, unit = bx >> 1;
    int m0 = mtile * 128;
    const unsigned short* Bp;
    const unsigned short* Ap;
    float* pout;
    int bstr, ncol0;
    if (unit < 144) {
        int nt = unit % 24;
        int kidx = unit / 24;          // 0..5
        int ksel = kidx >> 1, khalf = kidx & 1;
        ncol0 = nt * 128;
        Bp = WtG + (size_t)ncol0 * 3072 + ksel * 1024 + khalf * 512;
        bstr = 3072;
        Ap = Abf + ksel * 1024 + khalf * 512;
        pout = wbp + (size_t)kidx * 786432;
    } else {
        int su = unit - 144;           // 0..47
        int seg = su / 16;
        int rem = su % 16;
        int khalf = rem >> 3, nts = rem & 7;
        ncol0 = seg * 1024 + nts * 128;
        Bp = WtS + (size_t)seg * 1048576 + (size_t)(nts * 128) * 1024 + khalf * 512;
        bstr = 1024;
        Ap = Abf + seg * 1024 + khalf * 512;
        pout = Sp + (size_t)khalf * 786432;
    }

    int tid = threadIdx.x;
    int wave = tid >> 6, lane = tid & 63;
    int wm = wave >> 1, wn = wave & 1;
    int q = lane >> 4, lm = lane & 15;

    float4v acc[4][4];
    for (int i = 0; i < 4; ++i)
        for (int j = 0; j < 4; ++j)
            acc[i][j] = (float4v){0.f, 0.f, 0.f, 0.f};

    for (int kt = 0; kt < 512; kt += 64) {
        for (int rr = 0; rr < 4; ++rr) {
            int e = rr * 256 + tid;
            int row = e >> 3, cg = e & 7;
            *(uint4*)&As[row * 72 + cg * 8] =
                *(const uint4*)(Ap + (size_t)(m0 + row) * 3072 + kt + cg * 8);
            *(uint4*)&Bs[row * 72 + cg * 8] =
                *(const uint4*)(Bp + (size_t)row * bstr + kt + cg * 8);
        }
        __syncthreads();
        for (int ks = 0; ks < 64; ks += 32) {
            short8 av[4], bv[4];
            for (int i = 0; i < 4; ++i)
                av[i] = *(const short8*)&As[(wm * 64 + i * 16 + lm) * 72 + ks + q * 8];
            for (int j = 0; j < 4; ++j)
                bv[j] = *(const short8*)&Bs[(wn * 64 + j * 16 + lm) * 72 + ks + q * 8];
            for (int i = 0; i < 4; ++i)
                for (int j = 0; j < 4; ++j)
                    acc[i][j] = __builtin_amdgcn_mfma_f32_16x16x32_bf16(av[i], bv[j], acc[i][j], 0, 0, 0);
        }
        __syncthreads();
    }

    for (int i = 0; i < 4; ++i)
        for (int j = 0; j < 4; ++j) {
            int n = ncol0 + wn * 64 + j * 16 + lm;
            for (int reg = 0; reg < 4; ++reg) {
                int m = m0 + wm * 64 + i * 16 + q * 4 + reg;
                pout[(size_t)m * 3072 + n] = acc[i][j][reg];
            }
        }
}

// ---------------------------------------------------------------- final (fused sel2 + GRU epilogue)
__global__ __launch_bounds__(256) void k_final(const float* __restrict__ sg2,
                                               const float* __restrict__ mem,
                                               const float* __restrict__ wbp,
                                               const float* __restrict__ Sp,
                                               const float* __restrict__ h0,
                                               const float* __restrict__ bias,
                                               const float* __restrict__ b1,
                                               const float* __restrict__ b2,
                                               const float* __restrict__ b3,
                                               float* __restrict__ out) {
    __shared__ float svals[256];
    __shared__ int sidx[256];
    int b = blockIdx.x, t = threadIdx.x;
    svals[t] = sg2[b * MM + t];
    sidx[t] = t;
    __syncthreads();
    for (int s = 128; s > 0; s >>= 1) {
        if (t < s) {
            if (svals[t + s] > svals[t]) { svals[t] = svals[t + s]; sidx[t] = sidx[t + s]; }
        }
        __syncthreads();
    }
    int mstar = sidx[0];
    const float* erow = (mstar == 0) ? (h0 + (size_t)b * HH) : (mem + ((size_t)(b * MM + mstar)) * HH);
    float* o_row = out + (size_t)BB * HH + (size_t)b * 2 * HH;
    {
        int hb = t * 4;
        *(float4*)(o_row + HH + hb) = *(const float4*)(erow + hb);
    }
    int h = t * 4;
    size_t base = (size_t)b * 3072;
    float4 wsum[3];
#pragma unroll
    for (int g = 0; g < 3; ++g) {
        float4 a = make_float4(0.f, 0.f, 0.f, 0.f);
#pragma unroll
        for (int p = 0; p < 6; ++p) {
            float4 w = *(const float4*)(wbp + (size_t)p * 786432 + base + g * 1024 + h);
            a.x += w.x; a.y += w.y; a.z += w.z; a.w += w.w;
        }
        wsum[g] = a;
    }
    float4 bi0 = *(const float4*)(bias + h);
    float4 bi1 = *(const float4*)(bias + 1024 + h);
    float4 bi2 = *(const float4*)(bias + 2048 + h);
    float4 r4 = make_float4(sigmoidf_(wsum[0].x + bi0.x), sigmoidf_(wsum[0].y + bi0.y),
                            sigmoidf_(wsum[0].z + bi0.z), sigmoidf_(wsum[0].w + bi0.w));
    float4 z4 = make_float4(sigmoidf_(wsum[1].x + bi1.x), sigmoidf_(wsum[1].y + bi1.y),
                            sigmoidf_(wsum[1].z + bi1.z), sigmoidf_(wsum[1].w + bi1.w));
    float4 n4 = make_float4(sigmoidf_(wsum[2].x + bi2.x), sigmoidf_(wsum[2].y + bi2.y),
                            sigmoidf_(wsum[2].z + bi2.z), sigmoidf_(wsum[2].w + bi2.w));
    float4 s1, s2, s3;
    {
        float4 a0 = *(const float4*)(Sp + base + h);
        float4 a1 = *(const float4*)(Sp + 786432 + base + h);
        s1 = make_float4(a0.x + a1.x, a0.y + a1.y, a0.z + a1.z, a0.w + a1.w);
        a0 = *(const float4*)(Sp + base + 1024 + h);
        a1 = *(const float4*)(Sp + 786432 + base + 1024 + h);
        s2 = make_float4(a0.x + a1.x, a0.y + a1.y, a0.z + a1.z, a0.w + a1.w);
        a0 = *(const float4*)(Sp + base + 2048 + h);
        a1 = *(const float4*)(Sp + 786432 + base + 2048 + h);
        s3 = make_float4(a0.x + a1.x, a0.y + a1.y, a0.z + a1.z, a0.w + a1.w);
    }
    float4 v1 = *(const float4*)(b1 + h);
    float4 v2 = *(const float4*)(b2 + h);
    float4 v3 = *(const float4*)(b3 + h);
    float4 h0v = *(const float4*)(h0 + (size_t)b * HH + h);
    float4 hn, h1;
    hn.x = tanhf(s1.x + v1.x + r4.x * (s2.x + v2.x) + z4.x * (s3.x + v3.x));
    hn.y = tanhf(s1.y + v1.y + r4.y * (s2.y + v2.y) + z4.y * (s3.y + v3.y));
    hn.z = tanhf(s1.z + v1.z + r4.z * (s2.z + v2.z) + z4.z * (s3.z + v3.z));
    hn.w = tanhf(s1.w + v1.w + r4.w * (s2.w + v2.w) + z4.w * (s3.w + v3.w));
    h1.x = n4.x * hn.x + (1.f - n4.x) * h0v.x;
    h1.y = n4.y * hn.y + (1.f - n4.y) * h0v.y;
    h1.z = n4.z * hn.z + (1.f - n4.z) * h0v.z;
    h1.w = n4.w * hn.w + (1.f - n4.w) * h0v.w;
    *(float4*)(out + (size_t)b * HH + h) = h1;
    *(float4*)(o_row + h) = h1;
}

extern "C" void kernel_launch(void* const* d_in, const int* in_sizes, int n_in,
                              void* d_out, int out_size, void* d_ws, size_t ws_size,
                              hipStream_t stream) {
    const float* input_ = (const float*)d_in[0];
    const float* h0 = (const float*)d_in[1];
    const float* mem = (const float*)d_in[2];
    const float* last_usage = (const float*)d_in[3];
    const float* u1 = (const float*)d_in[4];
    const float* u2 = (const float*)d_in[5];
    const float* W_ih = (const float*)d_in[6];
    const float* W_hh = (const float*)d_in[7];
    const float* W_rh = (const float*)d_in[8];
    const float* W_s1 = (const float*)d_in[9];
    const float* W_s2 = (const float*)d_in[10];
    const float* W_s3 = (const float*)d_in[11];
    const float* bias = (const float*)d_in[12];
    const float* W_im = (const float*)d_in[13];
    const float* W_hm = (const float*)d_in[14];
    const float* fc1_w = (const float*)d_in[15];
    const float* fc1_b = (const float*)d_in[16];
    const float* W_im1 = (const float*)d_in[17];
    const float* W_hm1 = (const float*)d_in[18];
    const float* W_mm1 = (const float*)d_in[19];
    const float* bias_m1 = (const float*)d_in[20];
    const float* bias_1 = (const float*)d_in[21];
    const float* bias_2 = (const float*)d_in[22];
    const float* bias_3 = (const float*)d_in[23];
    float* out = (float*)d_out;

    float* ws = (float*)d_ws;
    float* sg1 = ws;                        // 65536
    float* sg2 = sg1 + 65536;               // 65536
    float* wbp = sg2 + 65536;               // 6 * 786432
    float* Sp = wbp + 6 * 786432;           // 2 * 786432
    unsigned short* Abf = (unsigned short*)(Sp + 2 * 786432);  // 786432 bf16
    unsigned short* WtG = Abf + 786432;     // 9437184 bf16
    unsigned short* WtS = WtG + 9437184;    // 3145728 bf16

    k_cvt_w<<<3072, 256, 0, stream>>>(W_ih, W_hh, W_rh, W_s1, W_s2, W_s3, WtG, WtS);
    k_score1<<<BB, 1024, 0, stream>>>(input_, h0, W_im, W_hm, fc1_w, fc1_b,
                                      mem, last_usage, u1, Abf, sg1);
    k_sel_score2<<<BB, 1024, 0, stream>>>(sg1, mem, h0, input_, W_im1, W_hm1, W_mm1, bias_m1,
                                          fc1_w, fc1_b, last_usage, u2, Abf, sg2);
    k_gemm<<<384, 256, 0, stream>>>(Abf, WtG, WtS, wbp, Sp);
    k_final<<<BB, 256, 0, stream>>>(sg2, mem, wbp, Sp, h0, bias, bias_1, bias_2, bias_3, out);
}